// Round 4
// baseline (98.391 us; speedup 1.0000x reference)
//
#include <hip/hip_runtime.h>
#include <hip/hip_bf16.h>

#define D_IN  2048
#define D_OUT 2048
#define M_TOTAL 8192   // B*S = 4*2048

typedef __attribute__((ext_vector_type(4))) float  f32x4;
typedef __attribute__((ext_vector_type(8))) short  short8;   // 8 bf16 for MFMA A/B frags
typedef __attribute__((ext_vector_type(4))) unsigned short u16x4;

typedef const __attribute__((address_space(1))) void gvoid_t;
typedef __attribute__((address_space(3))) void lvoid_t;

__device__ __forceinline__ unsigned short f2bf_rne(float f) {
    unsigned int u = __builtin_bit_cast(unsigned int, f);
    u = (u + 0x7FFFu + ((u >> 16) & 1u));
    return (unsigned short)(u >> 16);
}

// ---------------------------------------------------------------------------
// Kernel 1: per-block partial sums of |w| in fp64 (deterministic, no atomics)
// ---------------------------------------------------------------------------
__global__ __launch_bounds__(256) void absum_kernel(const float* __restrict__ w,
                                                    double* __restrict__ partials) {
    const int n4 = (D_OUT * D_IN) / 4;          // 1,048,576 float4s
    int tid = blockIdx.x * 256 + threadIdx.x;
    int stride = gridDim.x * 256;
    double s = 0.0;
    for (int i = tid; i < n4; i += stride) {
        float4 v = reinterpret_cast<const float4*>(w)[i];
        s += (double)fabsf(v.x) + (double)fabsf(v.y) +
             (double)fabsf(v.z) + (double)fabsf(v.w);
    }
    for (int off = 32; off; off >>= 1) s += __shfl_xor(s, off, 64);
    __shared__ double ls[4];
    if ((threadIdx.x & 63) == 0) ls[threadIdx.x >> 6] = s;
    __syncthreads();
    if (threadIdx.x == 0)
        partials[blockIdx.x] = ls[0] + ls[1] + ls[2] + ls[3];
}

// ---------------------------------------------------------------------------
// Kernel 2: ternary quantize -> bf16 [D_OUT][D_IN]; finalize folded in
// (every block reduces the 1024 partials identically -> deterministic)
// ---------------------------------------------------------------------------
__global__ __launch_bounds__(256) void quant_kernel(const float* __restrict__ w,
                                                    const double* __restrict__ partials,
                                                    unsigned short* __restrict__ wq) {
    int t = threadIdx.x;
    double s = partials[t] + partials[t + 256] + partials[t + 512] + partials[t + 768];
    for (int off = 32; off; off >>= 1) s += __shfl_xor(s, off, 64);
    __shared__ double ls[4];
    if ((t & 63) == 0) ls[t >> 6] = s;
    __syncthreads();
    double tot = ls[0] + ls[1] + ls[2] + ls[3];
    double inv = 1.0 / (tot / 4194304.0 + 1e-5);

    int i = blockIdx.x * 256 + t;                  // 1M threads, 4 elems each
    float4 v = reinterpret_cast<const float4*>(w)[i];
    u16x4 o;
    #pragma unroll
    for (int j = 0; j < 4; ++j) {
        float wf = (j == 0) ? v.x : (j == 1) ? v.y : (j == 2) ? v.z : v.w;
        double r = rint((double)wf * inv);
        r = fmin(1.0, fmax(-1.0, r));
        float f = (float)r;                         // exactly -1, 0, or 1
        o[j] = (unsigned short)(__builtin_bit_cast(unsigned int, f) >> 16);
    }
    *reinterpret_cast<u16x4*>(&wq[i * 4]) = o;
}

// ---------------------------------------------------------------------------
// Kernel 3: fused LayerNorm (fp32 in) -> bf16 [M][D_IN]
// ---------------------------------------------------------------------------
__global__ __launch_bounds__(256) void ln_kernel(const float* __restrict__ x,
                                                 const float* __restrict__ gamma,
                                                 const float* __restrict__ beta,
                                                 unsigned short* __restrict__ xn) {
    int row = blockIdx.x;
    const float4* xr = reinterpret_cast<const float4*>(x + (size_t)row * D_IN);
    int t = threadIdx.x;
    float4 v0 = xr[t];
    float4 v1 = xr[t + 256];
    float s  = v0.x + v0.y + v0.z + v0.w + v1.x + v1.y + v1.z + v1.w;
    float sq = v0.x*v0.x + v0.y*v0.y + v0.z*v0.z + v0.w*v0.w
             + v1.x*v1.x + v1.y*v1.y + v1.z*v1.z + v1.w*v1.w;
    for (int off = 32; off; off >>= 1) {
        s  += __shfl_xor(s,  off, 64);
        sq += __shfl_xor(sq, off, 64);
    }
    __shared__ float lss[4], lqq[4];
    if ((t & 63) == 0) { lss[t >> 6] = s; lqq[t >> 6] = sq; }
    __syncthreads();
    s  = lss[0] + lss[1] + lss[2] + lss[3];
    sq = lqq[0] + lqq[1] + lqq[2] + lqq[3];
    float mu  = s * (1.0f / D_IN);
    float var = sq * (1.0f / D_IN) - mu * mu;
    float inv = rsqrtf(var + 1e-5f);

    const float4* g4 = reinterpret_cast<const float4*>(gamma);
    const float4* b4 = reinterpret_cast<const float4*>(beta);
    float4 g0 = g4[t], g1 = g4[t + 256];
    float4 b0 = b4[t], b1 = b4[t + 256];

    u16x4 o0, o1;
    o0[0] = f2bf_rne((v0.x - mu) * inv * g0.x + b0.x);
    o0[1] = f2bf_rne((v0.y - mu) * inv * g0.y + b0.y);
    o0[2] = f2bf_rne((v0.z - mu) * inv * g0.z + b0.z);
    o0[3] = f2bf_rne((v0.w - mu) * inv * g0.w + b0.w);
    o1[0] = f2bf_rne((v1.x - mu) * inv * g1.x + b1.x);
    o1[1] = f2bf_rne((v1.y - mu) * inv * g1.y + b1.y);
    o1[2] = f2bf_rne((v1.z - mu) * inv * g1.z + b1.z);
    o1[3] = f2bf_rne((v1.w - mu) * inv * g1.w + b1.w);

    unsigned short* orow = xn + (size_t)row * D_IN;
    *reinterpret_cast<u16x4*>(&orow[t * 4])        = o0;
    *reinterpret_cast<u16x4*>(&orow[1024 + t * 4]) = o1;
}

// ---------------------------------------------------------------------------
// Kernel 4: 256x256-tile 8-wave deep-pipelined bf16 MFMA GEMM
// R3 change: SPLIT the per-K-tile vmcnt into two counted waits (ph1: vmcnt(8)
// drains kh1(T+1); ph3: vmcnt(8) drains kh0(T+2)'s predecessors). Min
// issue->drain span grows 2.5 -> 4 phases, covering L2/L3 latency. Ledger:
//   after T.ph3 wait, outstanding = {A,B}-kh1(T+1) + {A,B}-kh0(T+2) = 8 loads.
//   T+1.ph1 wait (12->8) drains {A,B}-kh1(T+1)  (read in T+1.ph2/ph3).
//   T+1.ph3 wait (12->8) drains {A,B}-kh0(T+2)  (read in T+2.ph0/ph1).
// Tails: NT-2 -> <8,4>, NT-1 -> <0,none>. Barrier/staging structure unchanged.
// ---------------------------------------------------------------------------
#define BM 256
#define BN 256
#define BKT 64
#define NT (D_IN / BKT)        // 32
#define SLOT_BYTES 65536
#define B_OFF 32768
#define KH_BYTES 16384

__device__ __forceinline__ void stage_quantum(const unsigned short* __restrict__ gbase,
                                              int grow0, int kcol0,
                                              char* smem, int ldsbase, int tid) {
    const int lane = tid & 63;
    const int w    = tid >> 6;
    // pre-swizzled global column: slot_p ^ f(row), f(row)=((row>>1)&3)=(lane>>3)&3 here
    const int colx = (((lane & 3) ^ ((lane >> 3) & 3)) << 3);
    #pragma unroll
    for (int j = 0; j < 2; ++j) {
        const int c = w * 2 + j;                    // 1KB chunk id, 0..15
        const int r = c * 16 + (lane >> 2);         // row within 256
        const unsigned short* g = gbase + (size_t)(grow0 + r) * D_IN + (kcol0 + colx);
        char* l = smem + ldsbase + c * 1024 + lane * 16;   // linear: wave-uniform + lane*16
        __builtin_amdgcn_global_load_lds((gvoid_t*)g, (lvoid_t*)l, 16, 0, 0);
    }
}

__device__ __forceinline__ short8 rdfrag(const char* smem, int off) {
    return *reinterpret_cast<const short8*>(smem + off);
}

template<int W>
__device__ __forceinline__ void vm_wait() {
    if constexpr (W == 8) {
        asm volatile("s_waitcnt vmcnt(8)" ::: "memory");
        __builtin_amdgcn_sched_barrier(0);
    } else if constexpr (W == 4) {
        asm volatile("s_waitcnt vmcnt(4)" ::: "memory");
        __builtin_amdgcn_sched_barrier(0);
    } else if constexpr (W == 0) {
        asm volatile("s_waitcnt vmcnt(0)" ::: "memory");
        __builtin_amdgcn_sched_barrier(0);
    }
    // W == -1: no wait
}

#define MFMA_CLUSTER_W(ACCROW, AFR, BFR, W)                                     \
    asm volatile("s_barrier" ::: "memory");                                     \
    __builtin_amdgcn_sched_barrier(0);                                          \
    __builtin_amdgcn_s_setprio(1);                                              \
    _Pragma("unroll")                                                           \
    for (int m = 0; m < 4; ++m)                                                 \
        _Pragma("unroll")                                                       \
        for (int n = 0; n < 4; ++n)                                             \
            acc[ACCROW + m][n] = __builtin_amdgcn_mfma_f32_16x16x32_bf16(       \
                AFR[m], BFR[n], acc[ACCROW + m][n], 0, 0, 0);                   \
    __builtin_amdgcn_s_setprio(0);                                              \
    __builtin_amdgcn_sched_barrier(0);                                          \
    vm_wait<W>();                                                               \
    asm volatile("s_barrier" ::: "memory");

template<bool S1, bool S2, int W1, int W3>
__device__ __forceinline__ void gemm_body(int T,
        const unsigned short* __restrict__ A, const unsigned short* __restrict__ B,
        int bm, int bn, char* smem, int tid, int aBase, int bBase,
        f32x4 (&acc)[8][4]) {
    const int sb = (T & 1) * SLOT_BYTES;
    const int so = sb ^ SLOT_BYTES;

    // ---- phase 0: (m0-3, kh0) ----
    short8 a0[4], b0[4];
    #pragma unroll
    for (int f = 0; f < 4; ++f) a0[f] = rdfrag(smem, sb + aBase + f * 1024);
    #pragma unroll
    for (int n = 0; n < 4; ++n) b0[n] = rdfrag(smem, sb + bBase + n * 1024);
    if (S1) stage_quantum(A, bm, (T + 1) * BKT + 32, smem, so + KH_BYTES, tid);
    MFMA_CLUSTER_W(0, a0, b0, -1)

    // ---- phase 1: (m4-7, kh0) ----
    short8 a1[4];
    #pragma unroll
    for (int f = 0; f < 4; ++f) a1[f] = rdfrag(smem, sb + aBase + 4096 + f * 1024);
    if (S1) stage_quantum(B, bn, (T + 1) * BKT + 32, smem, so + B_OFF + KH_BYTES, tid);
    MFMA_CLUSTER_W(4, a1, b0, W1)

    // ---- phase 2: (m0-3, kh1) ----
    short8 a2[4], b1[4];
    #pragma unroll
    for (int f = 0; f < 4; ++f) a2[f] = rdfrag(smem, sb + KH_BYTES + aBase + f * 1024);
    #pragma unroll
    for (int n = 0; n < 4; ++n) b1[n] = rdfrag(smem, sb + KH_BYTES + bBase + n * 1024);
    if (S2) stage_quantum(A, bm, (T + 2) * BKT, smem, sb, tid);
    MFMA_CLUSTER_W(0, a2, b1, -1)

    // ---- phase 3: (m4-7, kh1) ----
    short8 a3[4];
    #pragma unroll
    for (int f = 0; f < 4; ++f) a3[f] = rdfrag(smem, sb + KH_BYTES + aBase + 4096 + f * 1024);
    if (S2) stage_quantum(B, bn, (T + 2) * BKT, smem, sb + B_OFF, tid);
    MFMA_CLUSTER_W(4, a3, b1, W3)
}

__global__ __launch_bounds__(512, 2) void gemm256_kernel(const unsigned short* __restrict__ A,
                                                         const unsigned short* __restrict__ B,
                                                         const float* __restrict__ bias,
                                                         float* __restrict__ C) {
    extern __shared__ char smem[];
    const int tid  = threadIdx.x;
    const int lane = tid & 63;
    const int wid  = tid >> 6;
    const int wm   = wid >> 2;           // 0..1
    const int wn   = wid & 3;            // 0..3

    // XCD-aware bijective swizzle (grid=256, 256%8==0): each XCD owns 4
    // contiguous M-panels (4MB A in its private L2)
    const int orig = blockIdx.y * gridDim.x + blockIdx.x;   // 0..255
    const int swz  = (orig & 7) * 32 + (orig >> 3);
    const int bm   = (swz >> 3) * BM;
    const int bn   = (swz & 7) * BN;

    const int lr   = lane & 15;
    // swizzled per-lane ds_read base: row=lr, slot = (lane>>4) ^ ((lr>>1)&3)
    const int rdbase = lr * 64 + ((((lane >> 4) ^ ((lr >> 1) & 3))) << 4);
    const int aBase = wm * 8192 + rdbase;
    const int bBase = B_OFF + wn * 4096 + rdbase;

    f32x4 acc[8][4];
    #pragma unroll
    for (int m = 0; m < 8; ++m)
        #pragma unroll
        for (int n = 0; n < 4; ++n)
            acc[m][n] = (f32x4){0.f, 0.f, 0.f, 0.f};

    // prologue: tile0 fully, tile1 kh0; vmcnt(4) leaves tile1-kh0 in flight
    stage_quantum(A, bm, 0,  smem, 0,                          tid);
    stage_quantum(B, bn, 0,  smem, B_OFF,                      tid);
    stage_quantum(A, bm, 32, smem, KH_BYTES,                   tid);
    stage_quantum(B, bn, 32, smem, B_OFF + KH_BYTES,           tid);
    stage_quantum(A, bm, 64, smem, SLOT_BYTES,                 tid);
    stage_quantum(B, bn, 64, smem, SLOT_BYTES + B_OFF,         tid);
    asm volatile("s_waitcnt vmcnt(4)" ::: "memory");
    __builtin_amdgcn_sched_barrier(0);
    asm volatile("s_barrier" ::: "memory");

    for (int T = 0; T < NT - 2; ++T)
        gemm_body<true, true, 8, 8>(T, A, B, bm, bn, smem, tid, aBase, bBase, acc);
    gemm_body<true,  false, 8,  4>(NT - 2, A, B, bm, bn, smem, tid, aBase, bBase, acc);
    gemm_body<false, false, 0, -1>(NT - 1, A, B, bm, bn, smem, tid, aBase, bBase, acc);

    // ---- epilogue: per-wave LDS repack -> dwordx4 stores (256B segments) ----
    const int EST = 272;                       // row stride bytes (68 dwords, anti-conflict pad)
    char* eb = smem + wid * (16 * EST);        // 4352 B per wave
    const int C0 = bn + wn * 64;
    const int R0 = bm + wm * 128;
    const int rowsub = (lane >> 4) * 4;
    float bv[4];
    #pragma unroll
    for (int n = 0; n < 4; ++n) bv[n] = bias[C0 + n * 16 + lr];

    #pragma unroll
    for (int m = 0; m < 8; ++m) {
        #pragma unroll
        for (int n = 0; n < 4; ++n)
            #pragma unroll
            for (int i = 0; i < 4; ++i)
                *reinterpret_cast<float*>(eb + (rowsub + i) * EST + (n * 16 + lr) * 4)
                    = acc[m][n][i] + bv[n];
        #pragma unroll
        for (int q = 0; q < 4; ++q) {
            const int row = (lane >> 4) + q * 4;
            f32x4 v = *reinterpret_cast<const f32x4*>(eb + row * EST + lr * 16);
            *reinterpret_cast<f32x4*>(&C[(size_t)(R0 + m * 16 + row) * D_OUT + C0 + lr * 4]) = v;
        }
    }
}

// ---------------------------------------------------------------------------
extern "C" void kernel_launch(void* const* d_in, const int* in_sizes, int n_in,
                              void* d_out, int out_size, void* d_ws, size_t ws_size,
                              hipStream_t stream) {
    const float* x     = (const float*)d_in[0];   // [4,2048,2048]
    const float* w     = (const float*)d_in[1];   // [2048,2048]
    const float* bias  = (const float*)d_in[2];   // [2048]
    const float* gamma = (const float*)d_in[3];   // [2048]
    const float* beta  = (const float*)d_in[4];   // [2048]
    float* out = (float*)d_out;

    char* ws = (char*)d_ws;
    double* partials = (double*)ws;                               // 8KB
    unsigned short* wq = (unsigned short*)(ws + 16384);           // 8 MB bf16 [N][K]
    unsigned short* xn = (unsigned short*)(ws + 16384 + 8ull*1024*1024); // 32 MB bf16 [M][K]

    hipFuncSetAttribute(reinterpret_cast<const void*>(gemm256_kernel),
                        hipFuncAttributeMaxDynamicSharedMemorySize, 131072);

    absum_kernel   <<<1024, 256, 0, stream>>>(w, partials);
    quant_kernel   <<<4096, 256, 0, stream>>>(w, partials, wq);
    ln_kernel      <<<M_TOTAL, 256, 0, stream>>>(x, gamma, beta, xn);
    gemm256_kernel <<<dim3(D_OUT / BN, M_TOTAL / BM), 512, 131072, stream>>>(xn, wq, bias, out);
}

// Round 5
// 93.343 us; speedup vs baseline: 1.0541x; 1.0541x over previous
//
#include <hip/hip_runtime.h>
#include <hip/hip_bf16.h>

#define D_IN  2048
#define D_OUT 2048
#define M_TOTAL 8192   // B*S = 4*2048

typedef __attribute__((ext_vector_type(4))) float  f32x4;
typedef __attribute__((ext_vector_type(8))) short  short8;   // 8 bf16 for MFMA A/B frags
typedef __attribute__((ext_vector_type(4))) unsigned short u16x4;

typedef const __attribute__((address_space(1))) void gvoid_t;
typedef __attribute__((address_space(3))) void lvoid_t;

__device__ __forceinline__ unsigned short f2bf_rne(float f) {
    unsigned int u = __builtin_bit_cast(unsigned int, f);
    u = (u + 0x7FFFu + ((u >> 16) & 1u));
    return (unsigned short)(u >> 16);
}

// ---------------------------------------------------------------------------
// Kernel 1: per-block partial sums of |w| in fp64 (deterministic, no atomics)
// ---------------------------------------------------------------------------
__global__ __launch_bounds__(256) void absum_kernel(const float* __restrict__ w,
                                                    double* __restrict__ partials) {
    const int n4 = (D_OUT * D_IN) / 4;          // 1,048,576 float4s
    int tid = blockIdx.x * 256 + threadIdx.x;
    int stride = gridDim.x * 256;
    double s = 0.0;
    for (int i = tid; i < n4; i += stride) {
        float4 v = reinterpret_cast<const float4*>(w)[i];
        s += (double)fabsf(v.x) + (double)fabsf(v.y) +
             (double)fabsf(v.z) + (double)fabsf(v.w);
    }
    for (int off = 32; off; off >>= 1) s += __shfl_xor(s, off, 64);
    __shared__ double ls[4];
    if ((threadIdx.x & 63) == 0) ls[threadIdx.x >> 6] = s;
    __syncthreads();
    if (threadIdx.x == 0)
        partials[blockIdx.x] = ls[0] + ls[1] + ls[2] + ls[3];
}

// ---------------------------------------------------------------------------
// Kernel 2: ternary quantize -> bf16 [D_OUT][D_IN]; finalize folded in
// ---------------------------------------------------------------------------
__global__ __launch_bounds__(256) void quant_kernel(const float* __restrict__ w,
                                                    const double* __restrict__ partials,
                                                    unsigned short* __restrict__ wq) {
    int t = threadIdx.x;
    double s = partials[t] + partials[t + 256] + partials[t + 512] + partials[t + 768];
    for (int off = 32; off; off >>= 1) s += __shfl_xor(s, off, 64);
    __shared__ double ls[4];
    if ((t & 63) == 0) ls[t >> 6] = s;
    __syncthreads();
    double tot = ls[0] + ls[1] + ls[2] + ls[3];
    double inv = 1.0 / (tot / 4194304.0 + 1e-5);

    int i = blockIdx.x * 256 + t;                  // 1M threads, 4 elems each
    float4 v = reinterpret_cast<const float4*>(w)[i];
    u16x4 o;
    #pragma unroll
    for (int j = 0; j < 4; ++j) {
        float wf = (j == 0) ? v.x : (j == 1) ? v.y : (j == 2) ? v.z : v.w;
        double r = rint((double)wf * inv);
        r = fmin(1.0, fmax(-1.0, r));
        float f = (float)r;                         // exactly -1, 0, or 1
        o[j] = (unsigned short)(__builtin_bit_cast(unsigned int, f) >> 16);
    }
    *reinterpret_cast<u16x4*>(&wq[i * 4]) = o;
}

// ---------------------------------------------------------------------------
// Kernel 3: fused LayerNorm (fp32 in) -> bf16 [M][D_IN]
// ---------------------------------------------------------------------------
__global__ __launch_bounds__(256) void ln_kernel(const float* __restrict__ x,
                                                 const float* __restrict__ gamma,
                                                 const float* __restrict__ beta,
                                                 unsigned short* __restrict__ xn) {
    int row = blockIdx.x;
    const float4* xr = reinterpret_cast<const float4*>(x + (size_t)row * D_IN);
    int t = threadIdx.x;
    float4 v0 = xr[t];
    float4 v1 = xr[t + 256];
    float s  = v0.x + v0.y + v0.z + v0.w + v1.x + v1.y + v1.z + v1.w;
    float sq = v0.x*v0.x + v0.y*v0.y + v0.z*v0.z + v0.w*v0.w
             + v1.x*v1.x + v1.y*v1.y + v1.z*v1.z + v1.w*v1.w;
    for (int off = 32; off; off >>= 1) {
        s  += __shfl_xor(s,  off, 64);
        sq += __shfl_xor(sq, off, 64);
    }
    __shared__ float lss[4], lqq[4];
    if ((t & 63) == 0) { lss[t >> 6] = s; lqq[t >> 6] = sq; }
    __syncthreads();
    s  = lss[0] + lss[1] + lss[2] + lss[3];
    sq = lqq[0] + lqq[1] + lqq[2] + lqq[3];
    float mu  = s * (1.0f / D_IN);
    float var = sq * (1.0f / D_IN) - mu * mu;
    float inv = rsqrtf(var + 1e-5f);

    const float4* g4 = reinterpret_cast<const float4*>(gamma);
    const float4* b4 = reinterpret_cast<const float4*>(beta);
    float4 g0 = g4[t], g1 = g4[t + 256];
    float4 b0 = b4[t], b1 = b4[t + 256];

    u16x4 o0, o1;
    o0[0] = f2bf_rne((v0.x - mu) * inv * g0.x + b0.x);
    o0[1] = f2bf_rne((v0.y - mu) * inv * g0.y + b0.y);
    o0[2] = f2bf_rne((v0.z - mu) * inv * g0.z + b0.z);
    o0[3] = f2bf_rne((v0.w - mu) * inv * g0.w + b0.w);
    o1[0] = f2bf_rne((v1.x - mu) * inv * g1.x + b1.x);
    o1[1] = f2bf_rne((v1.y - mu) * inv * g1.y + b1.y);
    o1[2] = f2bf_rne((v1.z - mu) * inv * g1.z + b1.z);
    o1[3] = f2bf_rne((v1.w - mu) * inv * g1.w + b1.w);

    unsigned short* orow = xn + (size_t)row * D_IN;
    *reinterpret_cast<u16x4*>(&orow[t * 4])        = o0;
    *reinterpret_cast<u16x4*>(&orow[1024 + t * 4]) = o1;
}

// ---------------------------------------------------------------------------
// Kernel 4: 256x256-tile 8-wave bf16 MFMA GEMM — R4: read-ahead pipeline.
// Per phase: issue NEXT phase's frag ds_reads (overlap this phase's MFMA on
// the LDS pipe), issue stage, MFMA on frags read LAST phase (compiler's
// auto-counted lgkmcnt keeps new reads in flight), counted vmcnt, ONE barrier.
// Slot layout (2 slots x 64KB): Akh0@0, Akh1@16K, Bkh0@32K, Bkh1@48K.
// Ledger (steady T): ph0 reads Akh0(T)[m4-7]; stages Akh1(T+1); vmcnt(6)
//   drains {Akh1,Bkh1}(T) for ph1's reads. ph1 reads {Akh1,Bkh1}(T)[m0-3/B];
//   stages Bkh1(T+1). ph2 reads Akh1(T)[m4-7]; stages Akh0(T+2); vmcnt(6)
//   drains {Akh0,Bkh0}(T+1) for ph3's reads. ph3 reads {Akh0,Bkh0}(T+1);
//   stages Bkh0(T+2). Overwrite hazards: every region's last read drains
//   (auto-lgkm before next cluster) >=1 barrier before its re-stage. Tails:
//   T=NT-2 <S1,!S2,6,4,rd>, T=NT-1 <!S1,!S2,0,-1,!rd>.
// ---------------------------------------------------------------------------
#define BM 256
#define BN 256
#define BKT 64
#define NT (D_IN / BKT)        // 32
#define SLOT_BYTES 65536

__device__ __forceinline__ void stage_quantum(const unsigned short* __restrict__ gbase,
                                              int grow0, int kcol0,
                                              char* smem, int ldsbase, int tid) {
    const int lane = tid & 63;
    const int w    = tid >> 6;
    // pre-swizzled global column: slot_p ^ f(row), f(row)=((row>>1)&3)=(lane>>3)&3 here
    const int colx = (((lane & 3) ^ ((lane >> 3) & 3)) << 3);
    #pragma unroll
    for (int j = 0; j < 2; ++j) {
        const int c = w * 2 + j;                    // 1KB chunk id, 0..15
        const int r = c * 16 + (lane >> 2);         // row within 256
        const unsigned short* g = gbase + (size_t)(grow0 + r) * D_IN + (kcol0 + colx);
        char* l = smem + ldsbase + c * 1024 + lane * 16;   // linear: wave-uniform + lane*16
        __builtin_amdgcn_global_load_lds((gvoid_t*)g, (lvoid_t*)l, 16, 0, 0);
    }
}

__device__ __forceinline__ short8 rdfrag(const char* smem, int off) {
    return *reinterpret_cast<const short8*>(smem + off);
}

template<int W>
__device__ __forceinline__ void vm_wait() {
    if constexpr (W == 6) {
        asm volatile("s_waitcnt vmcnt(6)" ::: "memory");
        __builtin_amdgcn_sched_barrier(0);
    } else if constexpr (W == 4) {
        asm volatile("s_waitcnt vmcnt(4)" ::: "memory");
        __builtin_amdgcn_sched_barrier(0);
    } else if constexpr (W == 0) {
        asm volatile("s_waitcnt vmcnt(0)" ::: "memory");
        __builtin_amdgcn_sched_barrier(0);
    }
    // W == -1: no wait
}

#define MFMA16(ROW, AV, BV)                                                     \
    __builtin_amdgcn_sched_barrier(0);                                          \
    __builtin_amdgcn_s_setprio(1);                                              \
    _Pragma("unroll")                                                           \
    for (int m_ = 0; m_ < 4; ++m_)                                              \
        _Pragma("unroll")                                                       \
        for (int n_ = 0; n_ < 4; ++n_)                                          \
            acc[ROW + m_][n_] = __builtin_amdgcn_mfma_f32_16x16x32_bf16(        \
                AV[m_], BV[n_], acc[ROW + m_][n_], 0, 0, 0);                    \
    __builtin_amdgcn_s_setprio(0);                                              \
    __builtin_amdgcn_sched_barrier(0);

template<bool S1, bool S2, int W0, int W2, bool RD3>
__device__ __forceinline__ void ktile(int T,
        const unsigned short* __restrict__ A, const unsigned short* __restrict__ B,
        int bm, int bn, char* smem, int tid, int aBase, int bBase,
        short8 (&aS0)[4], short8 (&aS1)[4], short8 (&bE)[4], short8 (&bO)[4],
        f32x4 (&acc)[8][4]) {
    const int sb = (T & 1) * SLOT_BYTES;
    const int so = sb ^ SLOT_BYTES;

    // ---- ph0: cluster aS0 x bE -> acc[0..3] ----
    #pragma unroll
    for (int f = 0; f < 4; ++f) aS1[f] = rdfrag(smem, sb + aBase + 4096 + f * 1024);
    if (S1) stage_quantum(A, bm, (T + 1) * BKT + 32, smem, so + 16384, tid);
    MFMA16(0, aS0, bE)
    vm_wait<W0>();
    __builtin_amdgcn_s_barrier();

    // ---- ph1: cluster aS1 x bE -> acc[4..7] ----
    #pragma unroll
    for (int f = 0; f < 4; ++f) aS0[f] = rdfrag(smem, sb + 16384 + aBase + f * 1024);
    #pragma unroll
    for (int f = 0; f < 4; ++f) bO[f]  = rdfrag(smem, sb + 49152 + bBase + f * 1024);
    if (S1) stage_quantum(B, bn, (T + 1) * BKT + 32, smem, so + 49152, tid);
    MFMA16(4, aS1, bE)
    __builtin_amdgcn_s_barrier();

    // ---- ph2: cluster aS0 x bO -> acc[0..3] ----
    #pragma unroll
    for (int f = 0; f < 4; ++f) aS1[f] = rdfrag(smem, sb + 16384 + aBase + 4096 + f * 1024);
    if (S2) stage_quantum(A, bm, (T + 2) * BKT, smem, sb, tid);
    MFMA16(0, aS0, bO)
    vm_wait<W2>();
    __builtin_amdgcn_s_barrier();

    // ---- ph3: cluster aS1 x bO -> acc[4..7]; reads NEXT tile's ph0 frags ----
    if (RD3) {
        #pragma unroll
        for (int f = 0; f < 4; ++f) aS0[f] = rdfrag(smem, so + aBase + f * 1024);
        #pragma unroll
        for (int f = 0; f < 4; ++f) bE[f]  = rdfrag(smem, so + 32768 + bBase + f * 1024);
    }
    if (S2) stage_quantum(B, bn, (T + 2) * BKT, smem, sb + 32768, tid);
    MFMA16(4, aS1, bO)
    __builtin_amdgcn_s_barrier();
}

__global__ __launch_bounds__(512, 2) void gemm256_kernel(const unsigned short* __restrict__ A,
                                                         const unsigned short* __restrict__ B,
                                                         const float* __restrict__ bias,
                                                         float* __restrict__ C) {
    extern __shared__ char smem[];
    const int tid  = threadIdx.x;
    const int lane = tid & 63;
    const int wid  = tid >> 6;
    const int wm   = wid >> 2;           // 0..1
    const int wn   = wid & 3;            // 0..3

    // XCD-aware bijective swizzle (grid=256): each XCD owns 4 contiguous
    // M-panels (4MB A in its private L2)
    const int orig = blockIdx.y * gridDim.x + blockIdx.x;   // 0..255
    const int swz  = (orig & 7) * 32 + (orig >> 3);
    const int bm   = (swz >> 3) * BM;
    const int bn   = (swz & 7) * BN;

    const int lr   = lane & 15;
    // swizzled per-lane ds_read base: row=lr, slot = (lane>>4) ^ ((lr>>1)&3)
    const int rdbase = lr * 64 + ((((lane >> 4) ^ ((lr >> 1) & 3))) << 4);
    const int aBase = wm * 8192 + rdbase;
    const int bBase = wn * 4096 + rdbase;

    f32x4 acc[8][4];
    #pragma unroll
    for (int m = 0; m < 8; ++m)
        #pragma unroll
        for (int n = 0; n < 4; ++n)
            acc[m][n] = (f32x4){0.f, 0.f, 0.f, 0.f};

    short8 aS0[4], aS1[4], bE[4], bO[4];

    // prologue: tile0 all 4 quanta + tile1 kh0 pair; drain tile0-kh0 (oldest
    // 2 quanta) -> vmcnt(8); barrier; pre-read ph0(T=0) frags.
    stage_quantum(A, bm, 0,  smem, 0,                     tid);
    stage_quantum(B, bn, 0,  smem, 32768,                 tid);
    stage_quantum(A, bm, 32, smem, 16384,                 tid);
    stage_quantum(B, bn, 32, smem, 49152,                 tid);
    stage_quantum(A, bm, 64, smem, SLOT_BYTES,            tid);
    stage_quantum(B, bn, 64, smem, SLOT_BYTES + 32768,    tid);
    asm volatile("s_waitcnt vmcnt(8)" ::: "memory");
    __builtin_amdgcn_sched_barrier(0);
    __builtin_amdgcn_s_barrier();
    #pragma unroll
    for (int f = 0; f < 4; ++f) aS0[f] = rdfrag(smem, aBase + f * 1024);
    #pragma unroll
    for (int f = 0; f < 4; ++f) bE[f]  = rdfrag(smem, 32768 + bBase + f * 1024);
    __builtin_amdgcn_sched_barrier(0);

    for (int T = 0; T < NT - 2; ++T)
        ktile<true, true, 6, 6, true>(T, A, B, bm, bn, smem, tid, aBase, bBase,
                                      aS0, aS1, bE, bO, acc);
    ktile<true,  false, 6,  4, true >(NT - 2, A, B, bm, bn, smem, tid, aBase, bBase,
                                      aS0, aS1, bE, bO, acc);
    ktile<false, false, 0, -1, false>(NT - 1, A, B, bm, bn, smem, tid, aBase, bBase,
                                      aS0, aS1, bE, bO, acc);

    // ---- epilogue: per-wave LDS repack -> dwordx4 stores (256B segments) ----
    const int EST = 272;                       // row stride bytes (68 dwords, anti-conflict pad)
    char* eb = smem + wid * (16 * EST);        // 4352 B per wave
    const int C0 = bn + wn * 64;
    const int R0 = bm + wm * 128;
    const int rowsub = (lane >> 4) * 4;
    float bv[4];
    #pragma unroll
    for (int n = 0; n < 4; ++n) bv[n] = bias[C0 + n * 16 + lr];

    #pragma unroll
    for (int m = 0; m < 8; ++m) {
        #pragma unroll
        for (int n = 0; n < 4; ++n)
            #pragma unroll
            for (int i = 0; i < 4; ++i)
                *reinterpret_cast<float*>(eb + (rowsub + i) * EST + (n * 16 + lr) * 4)
                    = acc[m][n][i] + bv[n];
        #pragma unroll
        for (int q = 0; q < 4; ++q) {
            const int row = (lane >> 4) + q * 4;
            f32x4 v = *reinterpret_cast<const f32x4*>(eb + row * EST + lr * 16);
            *reinterpret_cast<f32x4*>(&C[(size_t)(R0 + m * 16 + row) * D_OUT + C0 + lr * 4]) = v;
        }
    }
}

// ---------------------------------------------------------------------------
extern "C" void kernel_launch(void* const* d_in, const int* in_sizes, int n_in,
                              void* d_out, int out_size, void* d_ws, size_t ws_size,
                              hipStream_t stream) {
    const float* x     = (const float*)d_in[0];   // [4,2048,2048]
    const float* w     = (const float*)d_in[1];   // [2048,2048]
    const float* bias  = (const float*)d_in[2];   // [2048]
    const float* gamma = (const float*)d_in[3];   // [2048]
    const float* beta  = (const float*)d_in[4];   // [2048]
    float* out = (float*)d_out;

    char* ws = (char*)d_ws;
    double* partials = (double*)ws;                               // 8KB
    unsigned short* wq = (unsigned short*)(ws + 16384);           // 8 MB bf16 [N][K]
    unsigned short* xn = (unsigned short*)(ws + 16384 + 8ull*1024*1024); // 32 MB bf16 [M][K]

    hipFuncSetAttribute(reinterpret_cast<const void*>(gemm256_kernel),
                        hipFuncAttributeMaxDynamicSharedMemorySize, 131072);

    absum_kernel   <<<1024, 256, 0, stream>>>(w, partials);
    quant_kernel   <<<4096, 256, 0, stream>>>(w, partials, wq);
    ln_kernel      <<<M_TOTAL, 256, 0, stream>>>(x, gamma, beta, xn);
    gemm256_kernel <<<dim3(D_OUT / BN, M_TOTAL / BM), 512, 131072, stream>>>(xn, wq, bias, out);
}